// Round 7
// baseline (27.193 us; speedup 1.0000x reference)
//
#include <hip/hip_runtime.h>

// TwoBodySplineScalarEmbed: out[e,c] = sum_b basis(x[e])_b * coeffs[cls[e], b, c]
// Quadratic uniform B-spline on [0,1], grid=5, NUM_BASIS=6; only 3 weights nonzero:
//   i0 = clamp(floor(4x),0,3), u = 4x-i0
//   w0 = (1-u)^2/2, w1 = -u^2+u+1/2, w2 = u^2/2   at basis rows i0..i0+2
//
// R6: the store loop was VALU-issue co-limited (weights recomputed by all 16
// lanes of a group). Precompute {w0,w1,w2,row_byte} per edge ONCE during the
// staging phase (edge-parallel); the store loop is then 1 weight ds_read +
// 3 coeff ds_read + 12 FMA + 1 store per iteration.
constexpr int NUM_TYPES    = 4;
constexpr int NUM_BASIS    = 6;
constexpr int CHANNELS     = 64;
constexpr int COEFF_FLOATS = NUM_TYPES * NUM_TYPES * NUM_BASIS * CHANNELS; // 6144 (24 KiB)
constexpr int KMAX  = 25;          // iterations per worker (grid 1280: 24-25)
constexpr int SLOTS = 16 * KMAX;   // 400 staged edges per block

typedef float f4 __attribute__((ext_vector_type(4)));

__global__ __launch_bounds__(256)
void TwoBodySplineScalarEmbed_kernel(const float* __restrict__ x,
                                     const int*   __restrict__ edge_types,
                                     const float* __restrict__ coeffs,
                                     float*       __restrict__ out,
                                     int E)
{
    __shared__ float sc[COEFF_FLOATS];
    __shared__ f4    sw[SLOTS];        // {w0, w1, w2, bitcast(coeff row byte offset)}
    // LDS: 24576 + 6400 = 30976 B -> 5 blocks/CU; grid 1280 = all co-resident.

    // Stage coefficient table (1536 f4 = 256 threads x 6).
    #pragma unroll
    for (int i = 0; i < COEFF_FLOATS / 4 / 256; ++i) {
        int idx = threadIdx.x + i * 256;
        reinterpret_cast<f4*>(sc)[idx] = reinterpret_cast<const f4*>(coeffs)[idx];
    }

    const int laneC  = threadIdx.x & 15;   // which float4 of the 64 channels
    const int grp    = threadIdx.x >> 4;   // 0..15: group index within block
    const int cb     = laneC * 16;         // byte offset within a coeff row
    const int stride = gridDim.x << 4;     // edges consumed per inner iteration

    for (int base = blockIdx.x << 4; base < E; base += stride * KMAX)
    {
        // Edge-parallel precompute of spline weights + coeff row offset.
        for (int s = threadIdx.x; s < SLOTS; s += 256) {
            int e = base + (s & 15) + (s >> 4) * stride;
            if (e < E) {
                float xj = fminf(fmaxf(x[e], 0.0f), 1.0f - 1e-6f);
                float s4 = xj * 4.0f;
                int   i0 = (int)s4;  i0 = i0 > 3 ? 3 : i0;
                float u  = s4 - (float)i0;
                float omu = 1.0f - u;
                int row = (edge_types[e] * NUM_TYPES + edge_types[E + e]) * NUM_BASIS + i0;
                f4 w;
                w.x = 0.5f * omu * omu;
                w.y = u * omu + 0.5f;
                w.z = 0.5f * u * u;
                w.w = __int_as_float(row * (CHANNELS * 4));   // byte offset into sc
                sw[s] = w;
            }
        }
        __syncthreads();

        // Minimal store loop: weight read + 3 coeff reads + 12 FMA + 1 store.
        for (int k = 0; k < KMAX; ++k) {
            int e = base + grp + k * stride;
            if (e >= E) break;
            f4 w = sw[(k << 4) + grp];
            const char* bp = reinterpret_cast<const char*>(sc)
                           + __float_as_int(w.w) + cb;
            f4 r0 = *reinterpret_cast<const f4*>(bp);
            f4 r1 = *reinterpret_cast<const f4*>(bp + 256);
            f4 r2 = *reinterpret_cast<const f4*>(bp + 512);

            f4 o = w.x * r0 + w.y * r1 + w.z * r2;
            *reinterpret_cast<f4*>(out + (size_t)e * CHANNELS + laneC * 4) = o;
        }
        __syncthreads();   // only matters if a second staging pass occurs
    }
}

extern "C" void kernel_launch(void* const* d_in, const int* in_sizes, int n_in,
                              void* d_out, int out_size, void* d_ws, size_t ws_size,
                              hipStream_t stream)
{
    const float* x          = (const float*)d_in[0];
    const int*   edge_types = (const int*)d_in[1];
    const float* coeffs     = (const float*)d_in[2];
    float*       out        = (float*)d_out;

    const int E = in_sizes[0];

    // 30.9 KiB LDS/block -> 5 blocks/CU; 256 CU * 5 = 1280 co-resident workers.
    int grid = (E + 15) / 16;
    if (grid > 1280) grid = 1280;

    TwoBodySplineScalarEmbed_kernel<<<grid, 256, 0, stream>>>(
        x, edge_types, coeffs, out, E);
}